// Round 15
// baseline (127.695 us; speedup 1.0000x reference)
//
#include <hip/hip_runtime.h>

typedef unsigned short u16;
typedef unsigned int u32;
using f32x4  = __attribute__((ext_vector_type(4))) float;
using u32x2  = __attribute__((ext_vector_type(2))) u32;
using u32x4  = __attribute__((ext_vector_type(4))) u32;
using bf16x8 = __attribute__((ext_vector_type(8))) short;

__device__ __forceinline__ u16 f2b(float f) {
  union { float f; u32 u; } v; v.f = f;
  return (u16)((v.u + 0x7FFFu + ((v.u >> 16) & 1u)) >> 16);
}
__device__ __forceinline__ float b2f(u16 u) {
  union { u32 u; float f; } v; v.u = ((u32)u) << 16;
  return v.f;
}
__device__ __forceinline__ u32 pk2(float a, float b) {
  u32 r;
  asm("v_cvt_pk_bf16_f32 %0, %1, %2" : "=v"(r) : "v"(a), "v"(b));
  return r;
}

// ---------------- K0: convert weights fp32 -> bf16 ----------------
__global__ __launch_bounds__(256) void kconvert(
    const float* __restrict__ Wqk, const float* __restrict__ Wv,
    const float* __restrict__ Wproj, u16* __restrict__ dst) {
  int e = (blockIdx.x * 256 + threadIdx.x) * 4;
  f32x4 v;
  if (e < 131072)      v = *(const f32x4*)(Wqk + e);
  else if (e < 196608) v = *(const f32x4*)(Wv + (e - 131072));
  else                 v = *(const f32x4*)(Wproj + (e - 196608));
  u32* d = (u32*)(dst + e);
  d[0] = (u32)f2b(v[0]) | ((u32)f2b(v[1]) << 16);
  d[1] = (u32)f2b(v[2]) | ((u32)f2b(v[3]) << 16);
}

// ---------------- K1: qk (token-major) + v (channel-major) GEMM ----------------
// 32-token tiles -> 512 blocks = 2 blocks/CU = 4 waves/SIMD (was 1 block/CU, 2).
// Staging traffic unchanged; per-element math identical to r13.
// K columns (ot in [16,32)) stored pre-scaled by log2(e)/sqrt(32).
__global__ __launch_bounds__(512) void kqkv(
    const float* __restrict__ x,
    const u16* __restrict__ Wqk_bf, const float* __restrict__ bqk,
    const u16* __restrict__ Wv_bf,  const float* __restrict__ bv,
    u16* __restrict__ qk_tm, u16* __restrict__ v_cm) {
  __shared__ __align__(16) u16 xs[32 * 264];   // [token][c], pitch 264
  const int bid = blockIdx.x;                  // 512 blocks
  const int b   = bid >> 7;
  const int n0  = (bid & 127) * 32;
  const int tid = threadIdx.x;

  { // stage x tile transposed: 256 c-rows x 32 tokens, fp32 -> bf16
    const int part = tid & 7, cr = tid >> 3;   // part 0..7, cr 0..63
    #pragma unroll
    for (int p = 0; p < 4; ++p) {
      const int c = p * 64 + cr;
      f32x4 v = *(const f32x4*)(x + (size_t)(b * 256 + c) * 4096 + n0 + part * 4);
      const int t0 = part * 4;
      xs[(t0 + 0) * 264 + c] = f2b(v[0]);
      xs[(t0 + 1) * 264 + c] = f2b(v[1]);
      xs[(t0 + 2) * 264 + c] = f2b(v[2]);
      xs[(t0 + 3) * 264 + c] = f2b(v[3]);
    }
  }
  __syncthreads();

  const int wave = tid >> 6, l = tid & 63, lg = l & 15, lq = l >> 4;
  const float kscale = 0.25503484f;  // log2(e)/sqrt(32), folded into stored K

  for (int ot = wave; ot < 48; ot += 8) {
    if (ot < 32) {
      // qk: D[token][o] = xs(A) * Wqk^T(B)
      bf16x8 bfr[8];
      const u16* wrow = Wqk_bf + (ot * 16 + lg) * 256 + lq * 8;
      #pragma unroll
      for (int kk = 0; kk < 8; ++kk) bfr[kk] = *(const bf16x8*)(wrow + kk * 32);
      const float bias = bqk[ot * 16 + lg];
      const float scl  = (ot >= 16) ? kscale : 1.0f;   // K columns pre-scaled
      #pragma unroll
      for (int ts = 0; ts < 2; ++ts) {
        f32x4 acc = {0.f, 0.f, 0.f, 0.f};
        #pragma unroll
        for (int kk = 0; kk < 8; ++kk) {
          bf16x8 af = *(const bf16x8*)(&xs[(ts * 16 + lg) * 264 + kk * 32 + lq * 8]);
          acc = __builtin_amdgcn_mfma_f32_16x16x32_bf16(af, bfr[kk], acc, 0, 0, 0);
        }
        u16* dst = qk_tm + (size_t)(b * 4096 + n0 + ts * 16 + lq * 4) * 512 + ot * 16 + lg;
        #pragma unroll
        for (int r = 0; r < 4; ++r) dst[(size_t)r * 512] = f2b((acc[r] + bias) * scl);
      }
    } else {
      // v: D[o][token] = Wv(A) * xs(B)  -> channel-major
      const int o2 = ot - 32;
      bf16x8 afw[8];
      const u16* wrow = Wv_bf + (o2 * 16 + lg) * 256 + lq * 8;
      #pragma unroll
      for (int kk = 0; kk < 8; ++kk) afw[kk] = *(const bf16x8*)(wrow + kk * 32);
      float bvr[4];
      #pragma unroll
      for (int r = 0; r < 4; ++r) bvr[r] = bv[o2 * 16 + lq * 4 + r];
      #pragma unroll
      for (int ts = 0; ts < 2; ++ts) {
        f32x4 acc = {0.f, 0.f, 0.f, 0.f};
        #pragma unroll
        for (int kk = 0; kk < 8; ++kk) {
          bf16x8 bfx = *(const bf16x8*)(&xs[(ts * 16 + lg) * 264 + kk * 32 + lq * 8]);
          acc = __builtin_amdgcn_mfma_f32_16x16x32_bf16(afw[kk], bfx, acc, 0, 0, 0);
        }
        #pragma unroll
        for (int r = 0; r < 4; ++r) {
          const int o = o2 * 16 + lq * 4 + r;
          v_cm[(size_t)(b * 256 + o) * 4096 + n0 + ts * 16 + lg] = f2b(acc[r] + bvr[r]);
        }
      }
    }
  }
}

// ---------------- K2: depthwise 5x5 conv (padding 2), 16-channel tiles ----------------
__global__ __launch_bounds__(256) void kdw(
    const u16* __restrict__ v_cm, const float* __restrict__ Wpe,
    const float* __restrict__ bpe, u16* __restrict__ pp) {
  __shared__ __align__(16) u16 vsh[5 * 16 * 64];  // [dy][c][w] = 10240 B
  __shared__ float wsh[16 * 25];                  // 1600 B
  const int bid = blockIdx.x;                      // 4096
  const int ct = bid & 15, h = (bid >> 4) & 63, b = bid >> 10;
  const int c0 = ct * 16;
  const int tid = threadIdx.x;

  for (int i = tid; i < 400; i += 256) wsh[i] = Wpe[(c0 + i / 25) * 25 + i % 25];
  #pragma unroll
  for (int uu = 0; uu < 3; ++uu) {
    const int u = uu * 256 + tid;
    if (u < 640) {
      const int dy = u >> 7, rem = u & 127, c = rem >> 3, part = rem & 7;
      const int hy = h + dy - 2;
      u32x4 val = {0, 0, 0, 0};
      if (hy >= 0 && hy < 64)
        val = *(const u32x4*)(v_cm + (size_t)(b * 256 + c0 + c) * 4096 + hy * 64 + part * 8);
      *(u32x4*)(&vsh[(dy * 16 + c) * 64 + part * 8]) = val;
    }
  }
  __syncthreads();

  const int c = tid >> 4, w0 = (tid & 15) * 4;
  float acc4[4];
  const float bias = bpe[c0 + c];
  #pragma unroll
  for (int i = 0; i < 4; ++i) acc4[i] = bias;
  const float* wc = &wsh[c * 25];
  #pragma unroll
  for (int dy = 0; dy < 5; ++dy) {
    const u16* row = &vsh[(dy * 16 + c) * 64];
    float rowv[8];
    #pragma unroll
    for (int j = 0; j < 8; ++j) {
      const int ww = w0 + j - 2;
      rowv[j] = (ww >= 0 && ww < 64) ? b2f(row[ww]) : 0.f;
    }
    #pragma unroll
    for (int dx = 0; dx < 5; ++dx) {
      const float wv = wc[dy * 5 + dx];
      #pragma unroll
      for (int wi = 0; wi < 4; ++wi) acc4[wi] += rowv[wi + dx] * wv;
    }
  }
  u32x2 o;
  o[0] = (u32)f2b(acc4[0]) | ((u32)f2b(acc4[1]) << 16);
  o[1] = (u32)f2b(acc4[2]) | ((u32)f2b(acc4[3]) << 16);
  u16* dst = pp + (size_t)(b * 256 + c0 + c) * 4096 + h * 64 + w0;
  *(u32x2*)(dst) = o;
}

// ---------------- K3: flash attention (r13 verbatim — FINAL, quarantined) ----------------
// qk_tm: (B*4096, 512): q at col [h*32..], k*kscale at col [256+h*32..]
// v_cm:  (B*256, 4096). out_tm: (B*4096, 256) bf16.
__global__ __launch_bounds__(256) void kattn(
    const u16* __restrict__ qk_tm, const u16* __restrict__ v_cm,
    u16* __restrict__ out_tm) {
  __shared__ __align__(16) char pbuf[4][32 * 128];  // per-wave P [q][k] bf16, XOR-swizzled

  const int bid = blockIdx.x;                     // 1024
  const int xcd = bid & 7, idx = bid >> 3;        // XCD swizzle: pair's 8 q-blocks share XCD
  const int pair = xcd * 16 + (idx >> 3);
  const int qb = idx & 7;
  const int h = pair & 7, ba = pair >> 3;
  const int b = ba >> 2, area = ba & 3;
  const size_t row_base = (size_t)b * 4096 + area * 1024;

  const int tid = threadIdx.x;
  const int wave = tid >> 6, l = tid & 63, lg = l & 15, lq = l >> 4;
  char* pbc = pbuf[wave];
  const int swz = (lg & 7) << 4;

  // Q fragments (B-operand)
  bf16x8 bQ[2];
  #pragma unroll
  for (int s = 0; s < 2; ++s) {
    const size_t qrow = row_base + qb * 128 + wave * 32 + s * 16 + lg;
    bQ[s] = *(const bf16x8*)(qk_tm + qrow * 512 + h * 32 + lq * 8);
  }

  const u16* Kbase = qk_tm + row_base * 512 + 256 + h * 32 + lq * 8;   // + ktok*512
  const u16* Vbase = v_cm + (size_t)(b * 256 + h * 32) * 4096 + area * 1024 + lq * 8;

  f32x4 accO[2][2];
  float dAcc[2] = {0.f, 0.f};
  #pragma unroll
  for (int s = 0; s < 2; ++s)
    #pragma unroll
    for (int d = 0; d < 2; ++d) accO[s][d] = (f32x4){0.f, 0.f, 0.f, 0.f};

  bf16x8 fK0[4], fV0[4], fK1[4], fV1[4];

  auto LOAD = [&](bf16x8* fK, bf16x8* fV, int kb) {
    #pragma unroll
    for (int t = 0; t < 4; ++t)
      fK[t] = *(const bf16x8*)(Kbase + (size_t)(kb * 64 + t * 16 + lg) * 512);
    #pragma unroll
    for (int kk = 0; kk < 2; ++kk)
      #pragma unroll
      for (int dt = 0; dt < 2; ++dt)
        fV[kk * 2 + dt] = *(const bf16x8*)(Vbase + (size_t)(dt * 16 + lg) * 4096 + kb * 64 + kk * 32);
  };

  auto COMP = [&](bf16x8* fK, bf16x8* fV) {
    // Swapped QK^T: D[ktok][q]; lane holds 4 consecutive ktok for q = s*16+lg
    f32x4 sc[2][4];
    #pragma unroll
    for (int s = 0; s < 2; ++s)
      #pragma unroll
      for (int t = 0; t < 4; ++t) {
        f32x4 z = {0.f, 0.f, 0.f, 0.f};
        sc[s][t] = __builtin_amdgcn_mfma_f32_16x16x32_bf16(fK[t], bQ[s], z, 0, 0, 0);
      }
    #pragma unroll
    for (int s = 0; s < 2; ++s)
      #pragma unroll
      for (int t = 0; t < 4; ++t) {
        const float e0 = __builtin_amdgcn_exp2f(sc[s][t][0]);
        const float e1 = __builtin_amdgcn_exp2f(sc[s][t][1]);
        const float e2 = __builtin_amdgcn_exp2f(sc[s][t][2]);
        const float e3 = __builtin_amdgcn_exp2f(sc[s][t][3]);
        dAcc[s] += (e0 + e1) + (e2 + e3);
        u32x2 w = {pk2(e0, e1), pk2(e2, e3)};
        *(u32x2*)(pbc + (s * 16 + lg) * 128 + ((t * 32 + lq * 8) ^ swz)) = w;
      }
    asm volatile("s_waitcnt lgkmcnt(0)" ::: "memory");
    __builtin_amdgcn_sched_barrier(0);
    // PV: O[q][d] += P * V^T
    #pragma unroll
    for (int s = 0; s < 2; ++s)
      #pragma unroll
      for (int kk = 0; kk < 2; ++kk) {
        bf16x8 aP = *(const bf16x8*)(pbc + (s * 16 + lg) * 128 + ((kk * 64 + lq * 16) ^ swz));
        #pragma unroll
        for (int dt = 0; dt < 2; ++dt)
          accO[s][dt] = __builtin_amdgcn_mfma_f32_16x16x32_bf16(aP, fV[kk * 2 + dt], accO[s][dt], 0, 0, 0);
      }
  };

  LOAD(fK0, fV0, 0);
  for (int kb = 0; kb < 16; kb += 2) {
    LOAD(fK1, fV1, kb + 1);
    COMP(fK0, fV0);
    if (kb + 2 < 16) LOAD(fK0, fV0, kb + 2);
    COMP(fK1, fV1);
  }

  // Denominators: lane (lg,lq) holds partial sum over its ktok subset for q=s*16+lg.
  #pragma unroll
  for (int s = 0; s < 2; ++s) {
    float d = dAcc[s];
    d += __shfl_xor(d, 16);
    d += __shfl_xor(d, 32);
    #pragma unroll
    for (int r = 0; r < 4; ++r) {
      const float den = __shfl(d, lq * 4 + r);   // full row sum for q=s*16+lq*4+r
      const float inv = __builtin_amdgcn_rcpf(den);
      const size_t row = row_base + qb * 128 + wave * 32 + s * 16 + lq * 4 + r;
      u16* dst = out_tm + row * 256 + h * 32 + lg;
      dst[0]  = f2b(accO[s][0][r] * inv);
      dst[16] = f2b(accO[s][1][r] * inv);
    }
  }
}

// ---------------- K4: (attn_out + pp) @ Wproj^T + bproj -> fp32 (B,C,H,W) ----------------
// 32-token tiles -> 512 blocks = 2 blocks/CU = 4 waves/SIMD (was 1 block/CU, 2).
__global__ __launch_bounds__(512) void kproj(
    const u16* __restrict__ out_tm, const u16* __restrict__ pp,
    const u16* __restrict__ Wproj_bf, const float* __restrict__ bproj,
    float* __restrict__ out) {
  __shared__ __align__(16) u16 as_[32 * 264];  // [token][c]
  const int bid = blockIdx.x;                  // 512
  const int b = bid >> 7;
  const int n0 = (bid & 127) * 32;
  const int tid = threadIdx.x;
  {
    const int r = tid >> 4, qp = tid & 15;     // r 0..31, qp 0..15 (2 chunks of 8 u16)
    const u16* src = out_tm + (size_t)(b * 4096 + n0 + r) * 256;
    *(u32x4*)(&as_[r * 264 + qp * 8])        = *(const u32x4*)(src + qp * 8);
    *(u32x4*)(&as_[r * 264 + (qp + 16) * 8]) = *(const u32x4*)(src + (qp + 16) * 8);
  }
  __syncthreads();
  {
    const int part = tid & 3;                  // 4 parts x 8 tokens = 32 tokens
    #pragma unroll
    for (int pass = 0; pass < 2; ++pass) {
      const int c = pass * 128 + (tid >> 2);
      u32x4 v = *(const u32x4*)(pp + (size_t)(b * 256 + c) * 4096 + n0 + part * 8);
      #pragma unroll
      for (int jj = 0; jj < 4; ++jj) {
        u32 w = v[jj];
        u16* q0 = &as_[(part * 8 + jj * 2) * 264 + c];
        *q0 = f2b(b2f(*q0) + b2f((u16)(w & 0xffffu)));
        u16* q1 = &as_[(part * 8 + jj * 2 + 1) * 264 + c];
        *q1 = f2b(b2f(*q1) + b2f((u16)(w >> 16)));
      }
    }
  }
  __syncthreads();
  const int wave = tid >> 6, l = tid & 63, lg = l & 15, lq = l >> 4;
  #pragma unroll
  for (int oi = 0; oi < 2; ++oi) {
    const int ot = oi * 8 + wave;
    bf16x8 afw[8];
    const u16* wrow = Wproj_bf + (ot * 16 + lg) * 256 + lq * 8;
    #pragma unroll
    for (int kk = 0; kk < 8; ++kk) afw[kk] = *(const bf16x8*)(wrow + kk * 32);
    float bpr[4];
    #pragma unroll
    for (int r = 0; r < 4; ++r) bpr[r] = bproj[ot * 16 + lq * 4 + r];
    #pragma unroll
    for (int ts = 0; ts < 2; ++ts) {
      f32x4 acc = {0.f, 0.f, 0.f, 0.f};
      #pragma unroll
      for (int kk = 0; kk < 8; ++kk) {
        bf16x8 bfx = *(const bf16x8*)(&as_[(ts * 16 + lg) * 264 + kk * 32 + lq * 8]);
        acc = __builtin_amdgcn_mfma_f32_16x16x32_bf16(afw[kk], bfx, acc, 0, 0, 0);
      }
      #pragma unroll
      for (int r = 0; r < 4; ++r) {
        const int o = ot * 16 + lq * 4 + r;
        out[(size_t)(b * 256 + o) * 4096 + n0 + ts * 16 + lg] = acc[r] + bpr[r];
      }
    }
  }
}

extern "C" void kernel_launch(void* const* d_in, const int* in_sizes, int n_in,
                              void* d_out, int out_size, void* d_ws, size_t ws_size,
                              hipStream_t stream) {
  const float* x     = (const float*)d_in[0];
  const float* Wqk   = (const float*)d_in[1];
  const float* bqk   = (const float*)d_in[2];
  const float* Wv    = (const float*)d_in[3];
  const float* bv    = (const float*)d_in[4];
  const float* Wpe   = (const float*)d_in[5];
  const float* bpe   = (const float*)d_in[6];
  const float* Wproj = (const float*)d_in[7];
  const float* bproj = (const float*)d_in[8];
  float* out = (float*)d_out;

  char* ws = (char*)d_ws;
  u16* qk_tm  = (u16*)(ws);                 // 16 MiB
  u16* v_cm   = (u16*)(ws + 16777216);      // 8 MiB
  u16* pp     = (u16*)(ws + 25165824);      // 8 MiB
  u16* out_tm = (u16*)(ws + 33554432);      // 8 MiB
  u16* wbf    = (u16*)(ws + 41943040);      // 512 KiB
  u16* Wqk_bf = wbf;
  u16* Wv_bf = wbf + 131072;
  u16* Wproj_bf = wbf + 196608;

  kconvert<<<256, 256, 0, stream>>>(Wqk, Wv, Wproj, wbf);
  kqkv<<<512, 512, 0, stream>>>(x, Wqk_bf, bqk, Wv_bf, bv, qk_tm, v_cm);
  kdw<<<4096, 256, 0, stream>>>(v_cm, Wpe, bpe, pp);
  kattn<<<1024, 256, 0, stream>>>(qk_tm, v_cm, out_tm);
  kproj<<<512, 512, 0, stream>>>(out_tm, pp, Wproj_bf, bproj, out);
}

// Round 16
// 118.257 us; speedup vs baseline: 1.0798x; 1.0798x over previous
//
#include <hip/hip_runtime.h>

typedef unsigned short u16;
typedef unsigned int u32;
using f32x4  = __attribute__((ext_vector_type(4))) float;
using u32x2  = __attribute__((ext_vector_type(2))) u32;
using u32x4  = __attribute__((ext_vector_type(4))) u32;
using bf16x8 = __attribute__((ext_vector_type(8))) short;

__device__ __forceinline__ u16 f2b(float f) {
  union { float f; u32 u; } v; v.f = f;
  return (u16)((v.u + 0x7FFFu + ((v.u >> 16) & 1u)) >> 16);
}
__device__ __forceinline__ float b2f(u16 u) {
  union { u32 u; float f; } v; v.u = ((u32)u) << 16;
  return v.f;
}
__device__ __forceinline__ u32 pk2(float a, float b) {
  u32 r;
  asm("v_cvt_pk_bf16_f32 %0, %1, %2" : "=v"(r) : "v"(a), "v"(b));
  return r;
}

// ---------------- K0: convert weights fp32 -> bf16 ----------------
__global__ __launch_bounds__(256) void kconvert(
    const float* __restrict__ Wqk, const float* __restrict__ Wv,
    const float* __restrict__ Wproj, u16* __restrict__ dst) {
  int e = (blockIdx.x * 256 + threadIdx.x) * 4;
  f32x4 v;
  if (e < 131072)      v = *(const f32x4*)(Wqk + e);
  else if (e < 196608) v = *(const f32x4*)(Wv + (e - 131072));
  else                 v = *(const f32x4*)(Wproj + (e - 196608));
  u32* d = (u32*)(dst + e);
  d[0] = (u32)f2b(v[0]) | ((u32)f2b(v[1]) << 16);
  d[1] = (u32)f2b(v[2]) | ((u32)f2b(v[3]) << 16);
}

// ---------------- K1: qk (token-major) + v (channel-major) GEMM ----------------
// 512 threads / 8 waves per block: 2 waves/SIMD for latency hiding.
// K columns (ot in [16,32)) are stored pre-scaled by log2(e)/sqrt(32).
__global__ __launch_bounds__(512) void kqkv(
    const float* __restrict__ x,
    const u16* __restrict__ Wqk_bf, const float* __restrict__ bqk,
    const u16* __restrict__ Wv_bf,  const float* __restrict__ bv,
    u16* __restrict__ qk_tm, u16* __restrict__ v_cm) {
  __shared__ __align__(16) u16 xs[64 * 264];   // [token][c], pitch 264
  const int bid = blockIdx.x;                  // 256 blocks
  const int b   = bid >> 6;
  const int n0  = (bid & 63) * 64;
  const int tid = threadIdx.x;

  { // stage x tile transposed: 256 c-rows x 64 tokens, fp32 -> bf16
    const int part = tid & 15, cr = tid >> 4;  // cr 0..31
    #pragma unroll
    for (int p = 0; p < 8; ++p) {
      const int c = p * 32 + cr;
      f32x4 v = *(const f32x4*)(x + (size_t)(b * 256 + c) * 4096 + n0 + part * 4);
      const int t0 = part * 4;
      xs[(t0 + 0) * 264 + c] = f2b(v[0]);
      xs[(t0 + 1) * 264 + c] = f2b(v[1]);
      xs[(t0 + 2) * 264 + c] = f2b(v[2]);
      xs[(t0 + 3) * 264 + c] = f2b(v[3]);
    }
  }
  __syncthreads();

  const int wave = tid >> 6, l = tid & 63, lg = l & 15, lq = l >> 4;
  const float kscale = 0.25503484f;  // log2(e)/sqrt(32), folded into stored K

  for (int ot = wave; ot < 48; ot += 8) {
    if (ot < 32) {
      // qk: D[token][o] = xs(A) * Wqk^T(B)
      bf16x8 bfr[8];
      const u16* wrow = Wqk_bf + (ot * 16 + lg) * 256 + lq * 8;
      #pragma unroll
      for (int kk = 0; kk < 8; ++kk) bfr[kk] = *(const bf16x8*)(wrow + kk * 32);
      const float bias = bqk[ot * 16 + lg];
      const float scl  = (ot >= 16) ? kscale : 1.0f;   // K columns pre-scaled
      #pragma unroll
      for (int ts = 0; ts < 4; ++ts) {
        f32x4 acc = {0.f, 0.f, 0.f, 0.f};
        #pragma unroll
        for (int kk = 0; kk < 8; ++kk) {
          bf16x8 af = *(const bf16x8*)(&xs[(ts * 16 + lg) * 264 + kk * 32 + lq * 8]);
          acc = __builtin_amdgcn_mfma_f32_16x16x32_bf16(af, bfr[kk], acc, 0, 0, 0);
        }
        u16* dst = qk_tm + (size_t)(b * 4096 + n0 + ts * 16 + lq * 4) * 512 + ot * 16 + lg;
        #pragma unroll
        for (int r = 0; r < 4; ++r) dst[(size_t)r * 512] = f2b((acc[r] + bias) * scl);
      }
    } else {
      // v: D[o][token] = Wv(A) * xs(B)  -> channel-major
      const int o2 = ot - 32;
      bf16x8 afw[8];
      const u16* wrow = Wv_bf + (o2 * 16 + lg) * 256 + lq * 8;
      #pragma unroll
      for (int kk = 0; kk < 8; ++kk) afw[kk] = *(const bf16x8*)(wrow + kk * 32);
      float bvr[4];
      #pragma unroll
      for (int r = 0; r < 4; ++r) bvr[r] = bv[o2 * 16 + lq * 4 + r];
      #pragma unroll
      for (int ts = 0; ts < 4; ++ts) {
        f32x4 acc = {0.f, 0.f, 0.f, 0.f};
        #pragma unroll
        for (int kk = 0; kk < 8; ++kk) {
          bf16x8 bfx = *(const bf16x8*)(&xs[(ts * 16 + lg) * 264 + kk * 32 + lq * 8]);
          acc = __builtin_amdgcn_mfma_f32_16x16x32_bf16(afw[kk], bfx, acc, 0, 0, 0);
        }
        #pragma unroll
        for (int r = 0; r < 4; ++r) {
          const int o = o2 * 16 + lq * 4 + r;
          v_cm[(size_t)(b * 256 + o) * 4096 + n0 + ts * 16 + lg] = f2b(acc[r] + bvr[r]);
        }
      }
    }
  }
}

// ---------------- K2: depthwise 5x5 conv (padding 2), 16-channel tiles ----------------
__global__ __launch_bounds__(256) void kdw(
    const u16* __restrict__ v_cm, const float* __restrict__ Wpe,
    const float* __restrict__ bpe, u16* __restrict__ pp) {
  __shared__ __align__(16) u16 vsh[5 * 16 * 64];  // [dy][c][w] = 10240 B
  __shared__ float wsh[16 * 25];                  // 1600 B
  const int bid = blockIdx.x;                      // 4096
  const int ct = bid & 15, h = (bid >> 4) & 63, b = bid >> 10;
  const int c0 = ct * 16;
  const int tid = threadIdx.x;

  for (int i = tid; i < 400; i += 256) wsh[i] = Wpe[(c0 + i / 25) * 25 + i % 25];
  #pragma unroll
  for (int uu = 0; uu < 3; ++uu) {
    const int u = uu * 256 + tid;
    if (u < 640) {
      const int dy = u >> 7, rem = u & 127, c = rem >> 3, part = rem & 7;
      const int hy = h + dy - 2;
      u32x4 val = {0, 0, 0, 0};
      if (hy >= 0 && hy < 64)
        val = *(const u32x4*)(v_cm + (size_t)(b * 256 + c0 + c) * 4096 + hy * 64 + part * 8);
      *(u32x4*)(&vsh[(dy * 16 + c) * 64 + part * 8]) = val;
    }
  }
  __syncthreads();

  const int c = tid >> 4, w0 = (tid & 15) * 4;
  float acc4[4];
  const float bias = bpe[c0 + c];
  #pragma unroll
  for (int i = 0; i < 4; ++i) acc4[i] = bias;
  const float* wc = &wsh[c * 25];
  #pragma unroll
  for (int dy = 0; dy < 5; ++dy) {
    const u16* row = &vsh[(dy * 16 + c) * 64];
    float rowv[8];
    #pragma unroll
    for (int j = 0; j < 8; ++j) {
      const int ww = w0 + j - 2;
      rowv[j] = (ww >= 0 && ww < 64) ? b2f(row[ww]) : 0.f;
    }
    #pragma unroll
    for (int dx = 0; dx < 5; ++dx) {
      const float wv = wc[dy * 5 + dx];
      #pragma unroll
      for (int wi = 0; wi < 4; ++wi) acc4[wi] += rowv[wi + dx] * wv;
    }
  }
  u32x2 o;
  o[0] = (u32)f2b(acc4[0]) | ((u32)f2b(acc4[1]) << 16);
  o[1] = (u32)f2b(acc4[2]) | ((u32)f2b(acc4[3]) << 16);
  u16* dst = pp + (size_t)(b * 256 + c0 + c) * 4096 + h * 64 + w0;
  *(u32x2*)(dst) = o;
}

// ---------------- K3: flash attention (FINAL, quarantined) ----------------
// qk_tm: (B*4096, 512): q at col [h*32..], k*kscale at col [256+h*32..]
// v_cm:  (B*256, 4096). out_tm: (B*4096, 256) bf16.
__global__ __launch_bounds__(256) void kattn(
    const u16* __restrict__ qk_tm, const u16* __restrict__ v_cm,
    u16* __restrict__ out_tm) {
  __shared__ __align__(16) char pbuf[4][32 * 128];  // per-wave P [q][k] bf16, XOR-swizzled

  const int bid = blockIdx.x;                     // 1024
  const int xcd = bid & 7, idx = bid >> 3;        // XCD swizzle: pair's 8 q-blocks share XCD
  const int pair = xcd * 16 + (idx >> 3);
  const int qb = idx & 7;
  const int h = pair & 7, ba = pair >> 3;
  const int b = ba >> 2, area = ba & 3;
  const size_t row_base = (size_t)b * 4096 + area * 1024;

  const int tid = threadIdx.x;
  const int wave = tid >> 6, l = tid & 63, lg = l & 15, lq = l >> 4;
  char* pbc = pbuf[wave];
  const int swz = (lg & 7) << 4;

  // Q fragments (B-operand)
  bf16x8 bQ[2];
  #pragma unroll
  for (int s = 0; s < 2; ++s) {
    const size_t qrow = row_base + qb * 128 + wave * 32 + s * 16 + lg;
    bQ[s] = *(const bf16x8*)(qk_tm + qrow * 512 + h * 32 + lq * 8);
  }

  const u16* Kbase = qk_tm + row_base * 512 + 256 + h * 32 + lq * 8;   // + ktok*512
  const u16* Vbase = v_cm + (size_t)(b * 256 + h * 32) * 4096 + area * 1024 + lq * 8;

  f32x4 accO[2][2];
  float dAcc[2] = {0.f, 0.f};
  #pragma unroll
  for (int s = 0; s < 2; ++s)
    #pragma unroll
    for (int d = 0; d < 2; ++d) accO[s][d] = (f32x4){0.f, 0.f, 0.f, 0.f};

  bf16x8 fK0[4], fV0[4], fK1[4], fV1[4];

  auto LOAD = [&](bf16x8* fK, bf16x8* fV, int kb) {
    #pragma unroll
    for (int t = 0; t < 4; ++t)
      fK[t] = *(const bf16x8*)(Kbase + (size_t)(kb * 64 + t * 16 + lg) * 512);
    #pragma unroll
    for (int kk = 0; kk < 2; ++kk)
      #pragma unroll
      for (int dt = 0; dt < 2; ++dt)
        fV[kk * 2 + dt] = *(const bf16x8*)(Vbase + (size_t)(dt * 16 + lg) * 4096 + kb * 64 + kk * 32);
  };

  auto COMP = [&](bf16x8* fK, bf16x8* fV) {
    // Swapped QK^T: D[ktok][q]; lane holds 4 consecutive ktok for q = s*16+lg
    f32x4 sc[2][4];
    #pragma unroll
    for (int s = 0; s < 2; ++s)
      #pragma unroll
      for (int t = 0; t < 4; ++t) {
        f32x4 z = {0.f, 0.f, 0.f, 0.f};
        sc[s][t] = __builtin_amdgcn_mfma_f32_16x16x32_bf16(fK[t], bQ[s], z, 0, 0, 0);
      }
    #pragma unroll
    for (int s = 0; s < 2; ++s)
      #pragma unroll
      for (int t = 0; t < 4; ++t) {
        const float e0 = __builtin_amdgcn_exp2f(sc[s][t][0]);
        const float e1 = __builtin_amdgcn_exp2f(sc[s][t][1]);
        const float e2 = __builtin_amdgcn_exp2f(sc[s][t][2]);
        const float e3 = __builtin_amdgcn_exp2f(sc[s][t][3]);
        dAcc[s] += (e0 + e1) + (e2 + e3);
        u32x2 w = {pk2(e0, e1), pk2(e2, e3)};
        *(u32x2*)(pbc + (s * 16 + lg) * 128 + ((t * 32 + lq * 8) ^ swz)) = w;
      }
    asm volatile("s_waitcnt lgkmcnt(0)" ::: "memory");
    __builtin_amdgcn_sched_barrier(0);
    // PV: O[q][d] += P * V^T
    #pragma unroll
    for (int s = 0; s < 2; ++s)
      #pragma unroll
      for (int kk = 0; kk < 2; ++kk) {
        bf16x8 aP = *(const bf16x8*)(pbc + (s * 16 + lg) * 128 + ((kk * 64 + lq * 16) ^ swz));
        #pragma unroll
        for (int dt = 0; dt < 2; ++dt)
          accO[s][dt] = __builtin_amdgcn_mfma_f32_16x16x32_bf16(aP, fV[kk * 2 + dt], accO[s][dt], 0, 0, 0);
      }
  };

  LOAD(fK0, fV0, 0);
  for (int kb = 0; kb < 16; kb += 2) {
    LOAD(fK1, fV1, kb + 1);
    COMP(fK0, fV0);
    if (kb + 2 < 16) LOAD(fK0, fV0, kb + 2);
    COMP(fK1, fV1);
  }

  // Denominators: lane (lg,lq) holds partial sum over its ktok subset for q=s*16+lg.
  #pragma unroll
  for (int s = 0; s < 2; ++s) {
    float d = dAcc[s];
    d += __shfl_xor(d, 16);
    d += __shfl_xor(d, 32);
    #pragma unroll
    for (int r = 0; r < 4; ++r) {
      const float den = __shfl(d, lq * 4 + r);   // full row sum for q=s*16+lq*4+r
      const float inv = __builtin_amdgcn_rcpf(den);
      const size_t row = row_base + qb * 128 + wave * 32 + s * 16 + lq * 4 + r;
      u16* dst = out_tm + row * 256 + h * 32 + lg;
      dst[0]  = f2b(accO[s][0][r] * inv);
      dst[16] = f2b(accO[s][1][r] * inv);
    }
  }
}

// ---------------- K4: (attn_out + pp) @ Wproj^T + bproj -> fp32 (B,C,H,W) ----------------
// 512 threads / 8 waves per block: 2 waves/SIMD.
__global__ __launch_bounds__(512) void kproj(
    const u16* __restrict__ out_tm, const u16* __restrict__ pp,
    const u16* __restrict__ Wproj_bf, const float* __restrict__ bproj,
    float* __restrict__ out) {
  __shared__ __align__(16) u16 as_[64 * 264];  // [token][c]
  const int bid = blockIdx.x;                  // 256
  const int b = bid >> 6;
  const int n0 = (bid & 63) * 64;
  const int tid = threadIdx.x;
  {
    const int r = tid >> 3, qp = tid & 7;      // r 0..63, qp 0..7
    const u32x4* src = (const u32x4*)(out_tm + (size_t)(b * 4096 + n0 + r) * 256 + qp * 32);
    #pragma unroll
    for (int j = 0; j < 4; ++j)
      *(u32x4*)(&as_[r * 264 + qp * 32 + j * 8]) = src[j];
  }
  __syncthreads();
  {
    const int part = tid & 7;
    #pragma unroll
    for (int pass = 0; pass < 4; ++pass) {
      const int c = pass * 64 + (tid >> 3);
      u32x4 v = *(const u32x4*)(pp + (size_t)(b * 256 + c) * 4096 + n0 + part * 8);
      #pragma unroll
      for (int jj = 0; jj < 4; ++jj) {
        u32 w = v[jj];
        u16* q0 = &as_[(part * 8 + jj * 2) * 264 + c];
        *q0 = f2b(b2f(*q0) + b2f((u16)(w & 0xffffu)));
        u16* q1 = &as_[(part * 8 + jj * 2 + 1) * 264 + c];
        *q1 = f2b(b2f(*q1) + b2f((u16)(w >> 16)));
      }
    }
  }
  __syncthreads();
  const int wave = tid >> 6, l = tid & 63, lg = l & 15, lq = l >> 4;
  #pragma unroll
  for (int oi = 0; oi < 2; ++oi) {
    const int ot = oi * 8 + wave;
    bf16x8 afw[8];
    const u16* wrow = Wproj_bf + (ot * 16 + lg) * 256 + lq * 8;
    #pragma unroll
    for (int kk = 0; kk < 8; ++kk) afw[kk] = *(const bf16x8*)(wrow + kk * 32);
    float bpr[4];
    #pragma unroll
    for (int r = 0; r < 4; ++r) bpr[r] = bproj[ot * 16 + lq * 4 + r];
    #pragma unroll
    for (int ts = 0; ts < 4; ++ts) {
      f32x4 acc = {0.f, 0.f, 0.f, 0.f};
      #pragma unroll
      for (int kk = 0; kk < 8; ++kk) {
        bf16x8 bfx = *(const bf16x8*)(&as_[(ts * 16 + lg) * 264 + kk * 32 + lq * 8]);
        acc = __builtin_amdgcn_mfma_f32_16x16x32_bf16(afw[kk], bfx, acc, 0, 0, 0);
      }
      #pragma unroll
      for (int r = 0; r < 4; ++r) {
        const int o = ot * 16 + lq * 4 + r;
        out[(size_t)(b * 256 + o) * 4096 + n0 + ts * 16 + lg] = acc[r] + bpr[r];
      }
    }
  }
}

extern "C" void kernel_launch(void* const* d_in, const int* in_sizes, int n_in,
                              void* d_out, int out_size, void* d_ws, size_t ws_size,
                              hipStream_t stream) {
  const float* x     = (const float*)d_in[0];
  const float* Wqk   = (const float*)d_in[1];
  const float* bqk   = (const float*)d_in[2];
  const float* Wv    = (const float*)d_in[3];
  const float* bv    = (const float*)d_in[4];
  const float* Wpe   = (const float*)d_in[5];
  const float* bpe   = (const float*)d_in[6];
  const float* Wproj = (const float*)d_in[7];
  const float* bproj = (const float*)d_in[8];
  float* out = (float*)d_out;

  char* ws = (char*)d_ws;
  u16* qk_tm  = (u16*)(ws);                 // 16 MiB
  u16* v_cm   = (u16*)(ws + 16777216);      // 8 MiB
  u16* pp     = (u16*)(ws + 25165824);      // 8 MiB
  u16* out_tm = (u16*)(ws + 33554432);      // 8 MiB
  u16* wbf    = (u16*)(ws + 41943040);      // 512 KiB
  u16* Wqk_bf = wbf;
  u16* Wv_bf = wbf + 131072;
  u16* Wproj_bf = wbf + 196608;

  kconvert<<<256, 256, 0, stream>>>(Wqk, Wv, Wproj, wbf);
  kqkv<<<256, 512, 0, stream>>>(x, Wqk_bf, bqk, Wv_bf, bv, qk_tm, v_cm);
  kdw<<<4096, 256, 0, stream>>>(v_cm, Wpe, bpe, pp);
  kattn<<<1024, 256, 0, stream>>>(qk_tm, v_cm, out_tm);
  kproj<<<256, 512, 0, stream>>>(out_tm, pp, Wproj_bf, bproj, out);
}